// Round 5
// baseline (102.241 us; speedup 1.0000x reference)
//
#include <hip/hip_runtime.h>
#include <hip/hip_bf16.h>
#include <stdint.h>

typedef __attribute__((ext_vector_type(8))) short bf16x8;
typedef __attribute__((ext_vector_type(4))) float f32x4;
using bf16 = __hip_bfloat16;

static constexpr int Mdim = 512;   // A batch
static constexpr int Ndim = 64;    // B batch
static constexpr int Cdim = 128;   // channels (K of the GEMM)
static constexpr int Pdim = 64;    // H*W positions
static constexpr float EPS_ADD = 0.001f;

#define SB0 __builtin_amdgcn_sched_barrier(0)
#define WAITV(N) asm volatile("s_waitcnt vmcnt(" #N ")" ::: "memory")

// ---------------------------------------------------------------------------
// async global->LDS, 16B per lane
// ---------------------------------------------------------------------------
__device__ __forceinline__ void gll16(const void* gsrc, void* ldst) {
    const __attribute__((address_space(1))) unsigned int* g =
        (const __attribute__((address_space(1))) unsigned int*)gsrc;
    __attribute__((address_space(3))) unsigned int* l =
        (__attribute__((address_space(3))) unsigned int*)(uintptr_t)ldst;
    __builtin_amdgcn_global_load_lds(g, l, 16, 0, 0);
}

// ---------------------------------------------------------------------------
// prep_A: A[M][C][P] f32  ->  Abf[(m*64+p)][c] bf16   (transpose C<->P + cast)
// ---------------------------------------------------------------------------
__global__ void prep_A_kernel(const float* __restrict__ A, bf16* __restrict__ Abf) {
    __shared__ float lds[128 * 65];
    const int m = blockIdx.x;
    const int t = threadIdx.x;
    const float* __restrict__ Am = A + (size_t)m * (Cdim * Pdim);

#pragma unroll
    for (int i = 0; i < 8; ++i) {
        int v = t + i * 256;
        int gidx = v * 4;
        int c = gidx >> 6, p = gidx & 63;
        float4 val = *reinterpret_cast<const float4*>(Am + gidx);
        float* dst = &lds[c * 65 + p];
        dst[0] = val.x; dst[1] = val.y; dst[2] = val.z; dst[3] = val.w;
    }
    __syncthreads();

    bf16* __restrict__ dstm = Abf + (size_t)m * (Pdim * Cdim);
#pragma unroll
    for (int i = 0; i < 16; ++i) {
        int pr = t + i * 256;
        int p = pr >> 6;
        int c = (pr & 63) << 1;
        float f0 = lds[c * 65 + p];
        float f1 = lds[(c + 1) * 65 + p];
        union { bf16 h[2]; unsigned u; } pk;
        pk.h[0] = __float2bfloat16(f0);
        pk.h[1] = __float2bfloat16(f1);
        *reinterpret_cast<unsigned*>(dstm + p * Cdim + c) = pk.u;
    }
}

// ---------------------------------------------------------------------------
// prep_G: Gbf[(n*64+q)][d] = bf16( sum_c B[n][c][q] * Wg[c][d] )
// ---------------------------------------------------------------------------
__global__ void prep_G_kernel(const float* __restrict__ B, const float* __restrict__ Wg,
                              bf16* __restrict__ Gbf) {
    __shared__ float ldsB[128 * 65];
    const int n  = blockIdx.x >> 2;
    const int q0 = (blockIdx.x & 3) * 16;
    const int t = threadIdx.x;
    const float* __restrict__ Bn = B + (size_t)n * (Cdim * Pdim);

#pragma unroll
    for (int i = 0; i < 8; ++i) {
        int v = t + i * 256;
        int gidx = v * 4;
        int c = gidx >> 6, q = gidx & 63;
        float4 val = *reinterpret_cast<const float4*>(Bn + gidx);
        float* dst = &ldsB[c * 65 + q];
        dst[0] = val.x; dst[1] = val.y; dst[2] = val.z; dst[3] = val.w;
    }
    __syncthreads();

    const int d  = t & 127;
    const int qb = q0 + (t >> 7) * 8;
    float acc[8] = {0.f, 0.f, 0.f, 0.f, 0.f, 0.f, 0.f, 0.f};
    for (int c = 0; c < 128; ++c) {
        float w = Wg[c * 128 + d];
#pragma unroll
        for (int qi = 0; qi < 8; ++qi)
            acc[qi] = fmaf(ldsB[c * 65 + qb + qi], w, acc[qi]);
    }
#pragma unroll
    for (int qi = 0; qi < 8; ++qi)
        Gbf[(size_t)(n * 64 + qb + qi) * Cdim + d] = __float2bfloat16(acc[qi]);
}

// ---------------------------------------------------------------------------
// gemm_max v3: rolling 3-buffer pipeline, distance-2 prefetch, ONE barrier +
// ONE counted vmcnt per K-half phase (8 phases per block). Never vmcnt(0)
// mid-loop; stores drained only when paired with a stale stage.
// block = 128 cols (2 n's) x 4 bm-tiles of 128 rows; G in registers.
// LDS: 3 x 16 KB = 48 KB -> 3 blocks/CU.
// Per-wave vmcnt event order: G(16), L0, L1 | C0 L2 | C1 L3 S0 | C2 L4 |
// C3 L5 S1 | C4 L6 | C5 L7 S2 | C6 | C7 S3  -> waits {4,4,8,8,8,8,8,4}.
// Buffer safety: stage(s+2) writes buf (s-1)%3 whose readers all passed the
// phase-s barrier; never touches buf s%3 or (s+1)%3.
// ---------------------------------------------------------------------------
__global__ __launch_bounds__(256, 3)
void gemm_max_kernel(const bf16* __restrict__ Abf, const bf16* __restrict__ Gbf,
                     float* __restrict__ out) {
    __shared__ bf16 sA[3 * 128 * 64];   // 3 rolling half-tile buffers, swizzled
    const int tid  = threadIdx.x;
    const int lane = tid & 63;
    const int w    = tid >> 6;
    const int wr = w >> 1, wc = w & 1;
    const int rr = lane & 15, g = lane >> 4;

    // bijective XCD swizzle (2048 % 8 == 0): same-bmg blocks share an XCD L2.
    const int wg  = (blockIdx.x & 7) * 256 + (blockIdx.x >> 3);
    const int bn  = wg & 31;   // 32 col-tiles of 128
    const int bmg = wg >> 5;   // 64 row-groups of 4x128 rows

    // ---- G fragments resident in registers (oldest vmcnt events) ----
    bf16x8 bfr[4][4];
    {
        const bf16* Gp = Gbf + ((size_t)(bn * 128 + wc * 64 + rr)) * 128 + g * 8;
#pragma unroll
        for (int ct = 0; ct < 4; ++ct)
#pragma unroll
            for (int ks = 0; ks < 4; ++ks)
                bfr[ct][ks] = *reinterpret_cast<const bf16x8*>(Gp + ct * 16 * 128 + ks * 32);
    }
    asm volatile("" ::: "memory");   // pin G-loads before stage issues

    const char* Abase = (const char*)(Abf + (size_t)bmg * 4 * 128 * 128);

    // stage K-half s (tile s>>1, half s&1) into buf s%3; 4 x 16B per thread.
    // LDS[row][b] = global[row][h*128 + (b ^ ((row&7)<<4))]  (16B-chunk XOR)
    auto stage = [&](int s) {
        const int it = s >> 1, h = s & 1, buf = s % 3;
        char* lbase = (char*)&sA[0] + buf * 16384;
#pragma unroll
        for (int j = 0; j < 4; ++j) {
            int f = (j * 256 + tid) * 16;
            int row = f >> 7;
            int inner = (f & 127) ^ ((row & 7) << 4);
            gll16(Abase + (size_t)it * 32768 + row * 256 + h * 128 + inner, lbase + f);
        }
    };

    f32x4 acc[4][4];
#pragma unroll
    for (int rt = 0; rt < 4; ++rt)
#pragma unroll
        for (int ct = 0; ct < 4; ++ct)
            acc[rt][ct] = (f32x4){0.f, 0.f, 0.f, 0.f};

    auto compute = [&](int s) {
        const int buf = s % 3, ksb = (s & 1) * 2;
        const char* lbase = (const char*)&sA[0] + buf * 16384;
#pragma unroll
        for (int kk = 0; kk < 2; ++kk) {
            const int kb = (kk * 64 + g * 16) ^ ((rr & 7) << 4);
            bf16x8 a[4];
#pragma unroll
            for (int rt = 0; rt < 4; ++rt)
                a[rt] = *reinterpret_cast<const bf16x8*>(lbase + (wr * 64 + rt * 16 + rr) * 128 + kb);
#pragma unroll
            for (int rt = 0; rt < 4; ++rt)
#pragma unroll
                for (int ct = 0; ct < 4; ++ct)
                    acc[rt][ct] = __builtin_amdgcn_mfma_f32_16x16x32_bf16(
                        a[rt], bfr[ct][ksb + kk], acc[rt][ct], 0, 0, 0);
        }
    };

    auto epilogue = [&](int it) {
        const int m = (bmg * 4 + it) * 2 + wr;
        const int n = bn * 2 + wc;
        float* obase = out + (size_t)m * 4096 + n * 64;
#pragma unroll
        for (int rt = 0; rt < 4; ++rt) {
            float v[4];
#pragma unroll
            for (int j = 0; j < 4; ++j)
                v[j] = fmaxf(fmaxf(acc[rt][0][j], acc[rt][1][j]),
                             fmaxf(acc[rt][2][j], acc[rt][3][j]));
#pragma unroll
            for (int off = 8; off >= 1; off >>= 1)
#pragma unroll
                for (int j = 0; j < 4; ++j)
                    v[j] = fmaxf(v[j], __shfl_xor(v[j], off));
            if (rr == 0) {
                float4 o;
                o.x = fmaxf(v[0], 0.f) + EPS_ADD;
                o.y = fmaxf(v[1], 0.f) + EPS_ADD;
                o.z = fmaxf(v[2], 0.f) + EPS_ADD;
                o.w = fmaxf(v[3], 0.f) + EPS_ADD;
                *reinterpret_cast<float4*>(obase + rt * 16 + g * 4) = o;
            }
#pragma unroll
            for (int ct = 0; ct < 4; ++ct)
                acc[rt][ct] = (f32x4){0.f, 0.f, 0.f, 0.f};
        }
    };

    // ---- prologue: stage(0), stage(1) in flight ----
    stage(0);
    stage(1);

    // ---- 8 phases: wait / barrier / compute / stage(s+2) / [epilogue] ----
    WAITV(4); __builtin_amdgcn_s_barrier(); SB0;   // drains G + stage0
    compute(0); SB0; stage(2); SB0;

    WAITV(4); __builtin_amdgcn_s_barrier(); SB0;   // drains stage1
    compute(1); SB0; stage(3); epilogue(0); SB0;

    WAITV(8); __builtin_amdgcn_s_barrier(); SB0;   // drains stage2
    compute(2); SB0; stage(4); SB0;

    WAITV(8); __builtin_amdgcn_s_barrier(); SB0;   // drains stage3
    compute(3); SB0; stage(5); epilogue(1); SB0;

    WAITV(8); __builtin_amdgcn_s_barrier(); SB0;   // drains S0 + stage4
    compute(4); SB0; stage(6); SB0;

    WAITV(8); __builtin_amdgcn_s_barrier(); SB0;   // drains stage5
    compute(5); SB0; stage(7); epilogue(2); SB0;

    WAITV(8); __builtin_amdgcn_s_barrier(); SB0;   // drains S1 + stage6
    compute(6); SB0;

    WAITV(4); __builtin_amdgcn_s_barrier(); SB0;   // drains stage7 (leaves S2)
    compute(7); SB0; epilogue(3);
}

// ---------------------------------------------------------------------------
extern "C" void kernel_launch(void* const* d_in, const int* in_sizes, int n_in,
                              void* d_out, int out_size, void* d_ws, size_t ws_size,
                              hipStream_t stream) {
    const float* A  = (const float*)d_in[0];
    const float* B  = (const float*)d_in[1];
    const float* Wg = (const float*)d_in[2];
    float* out = (float*)d_out;

    bf16* Abf = (bf16*)d_ws;                                        // 32768 x 128 bf16 = 8 MiB
    bf16* Gbf = (bf16*)((char*)d_ws + (size_t)Mdim * Pdim * Cdim * sizeof(bf16)); // 4096 x 128 bf16

    prep_A_kernel<<<Mdim, 256, 0, stream>>>(A, Abf);
    prep_G_kernel<<<256, 256, 0, stream>>>(B, Wg, Gbf);

    // rows = M*P = 32768 -> 64 groups of 512; cols = N*P = 4096 -> 32 tiles of 128
    constexpr int GEMM_GRID = (Mdim * Pdim / 512) * (Ndim * Pdim / 128);  // 2048
    gemm_max_kernel<<<GEMM_GRID, 256, 0, stream>>>(Abf, Gbf, out);
}

// Round 6
// 81.966 us; speedup vs baseline: 1.2474x; 1.2474x over previous
//
#include <hip/hip_runtime.h>
#include <hip/hip_bf16.h>
#include <stdint.h>

typedef __attribute__((ext_vector_type(8))) short bf16x8;
typedef __attribute__((ext_vector_type(4))) float f32x4;
using bf16 = __hip_bfloat16;

static constexpr int Mdim = 512;   // A batch
static constexpr int Ndim = 64;    // B batch
static constexpr int Cdim = 128;   // channels (K of the GEMM)
static constexpr int Pdim = 64;    // H*W positions
static constexpr float EPS_ADD = 0.001f;

#define SB0 __builtin_amdgcn_sched_barrier(0)
#define WAITV(N) asm volatile("s_waitcnt vmcnt(" #N ")" ::: "memory")

// ---------------------------------------------------------------------------
// async global->LDS, 16B per lane
// ---------------------------------------------------------------------------
__device__ __forceinline__ void gll16(const void* gsrc, void* ldst) {
    const __attribute__((address_space(1))) unsigned int* g =
        (const __attribute__((address_space(1))) unsigned int*)gsrc;
    __attribute__((address_space(3))) unsigned int* l =
        (__attribute__((address_space(3))) unsigned int*)(uintptr_t)ldst;
    __builtin_amdgcn_global_load_lds(g, l, 16, 0, 0);
}

// ---------------------------------------------------------------------------
// prep_A: A[M][C][P] f32  ->  Abf[(m*64+p)][c] bf16   (transpose C<->P + cast)
// ---------------------------------------------------------------------------
__global__ void prep_A_kernel(const float* __restrict__ A, bf16* __restrict__ Abf) {
    __shared__ float lds[128 * 65];
    const int m = blockIdx.x;
    const int t = threadIdx.x;
    const float* __restrict__ Am = A + (size_t)m * (Cdim * Pdim);

#pragma unroll
    for (int i = 0; i < 8; ++i) {
        int v = t + i * 256;
        int gidx = v * 4;
        int c = gidx >> 6, p = gidx & 63;
        float4 val = *reinterpret_cast<const float4*>(Am + gidx);
        float* dst = &lds[c * 65 + p];
        dst[0] = val.x; dst[1] = val.y; dst[2] = val.z; dst[3] = val.w;
    }
    __syncthreads();

    bf16* __restrict__ dstm = Abf + (size_t)m * (Pdim * Cdim);
#pragma unroll
    for (int i = 0; i < 16; ++i) {
        int pr = t + i * 256;
        int p = pr >> 6;
        int c = (pr & 63) << 1;
        float f0 = lds[c * 65 + p];
        float f1 = lds[(c + 1) * 65 + p];
        union { bf16 h[2]; unsigned u; } pk;
        pk.h[0] = __float2bfloat16(f0);
        pk.h[1] = __float2bfloat16(f1);
        *reinterpret_cast<unsigned*>(dstm + p * Cdim + c) = pk.u;
    }
}

// ---------------------------------------------------------------------------
// prep_G: Gbf[(n*64+q)][d] = bf16( sum_c B[n][c][q] * Wg[c][d] )
// ---------------------------------------------------------------------------
__global__ void prep_G_kernel(const float* __restrict__ B, const float* __restrict__ Wg,
                              bf16* __restrict__ Gbf) {
    __shared__ float ldsB[128 * 65];
    const int n  = blockIdx.x >> 2;
    const int q0 = (blockIdx.x & 3) * 16;
    const int t = threadIdx.x;
    const float* __restrict__ Bn = B + (size_t)n * (Cdim * Pdim);

#pragma unroll
    for (int i = 0; i < 8; ++i) {
        int v = t + i * 256;
        int gidx = v * 4;
        int c = gidx >> 6, q = gidx & 63;
        float4 val = *reinterpret_cast<const float4*>(Bn + gidx);
        float* dst = &ldsB[c * 65 + q];
        dst[0] = val.x; dst[1] = val.y; dst[2] = val.z; dst[3] = val.w;
    }
    __syncthreads();

    const int d  = t & 127;
    const int qb = q0 + (t >> 7) * 8;
    float acc[8] = {0.f, 0.f, 0.f, 0.f, 0.f, 0.f, 0.f, 0.f};
    for (int c = 0; c < 128; ++c) {
        float w = Wg[c * 128 + d];
#pragma unroll
        for (int qi = 0; qi < 8; ++qi)
            acc[qi] = fmaf(ldsB[c * 65 + qb + qi], w, acc[qi]);
    }
#pragma unroll
    for (int qi = 0; qi < 8; ++qi)
        Gbf[(size_t)(n * 64 + qb + qi) * Cdim + d] = __float2bfloat16(acc[qi]);
}

// ---------------------------------------------------------------------------
// gemm_max v3b: v3 pipeline (rolling 3 buffers, distance-2 prefetch, ONE
// barrier + ONE counted vmcnt per phase) with the spill fixed:
// __launch_bounds__(256,2) -> 256-reg unified budget (round-5's (256,3)
// squeezed to ~170 and spilled acc/bfr -> 100+ MB scratch HBM traffic).
// LDS 48 KB still allows 3 blocks/CU if the allocator lands <=170.
// Per-wave vmcnt event order: G(16), L0, L1 | C0 L2 | C1 L3 S0 | C2 L4 |
// C3 L5 S1 | C4 L6 | C5 L7 S2 | C6 | C7 S3  -> waits {4,4,8,8,8,8,8,4}.
// Buffer safety: stage(s+2) writes buf (s-1)%3 whose readers all passed the
// phase-s barrier; never touches buf s%3 or (s+1)%3.
// ---------------------------------------------------------------------------
__global__ __launch_bounds__(256, 2)
void gemm_max_kernel(const bf16* __restrict__ Abf, const bf16* __restrict__ Gbf,
                     float* __restrict__ out) {
    __shared__ bf16 sA[3 * 128 * 64];   // 3 rolling half-tile buffers, swizzled
    const int tid  = threadIdx.x;
    const int lane = tid & 63;
    const int w    = tid >> 6;
    const int wr = w >> 1, wc = w & 1;
    const int rr = lane & 15, g = lane >> 4;

    // bijective XCD swizzle (2048 % 8 == 0): same-bmg blocks share an XCD L2.
    const int wg  = (blockIdx.x & 7) * 256 + (blockIdx.x >> 3);
    const int bn  = wg & 31;   // 32 col-tiles of 128
    const int bmg = wg >> 5;   // 64 row-groups of 4x128 rows

    // ---- G fragments resident in registers (oldest vmcnt events) ----
    bf16x8 bfr[4][4];
    {
        const bf16* Gp = Gbf + ((size_t)(bn * 128 + wc * 64 + rr)) * 128 + g * 8;
#pragma unroll
        for (int ct = 0; ct < 4; ++ct)
#pragma unroll
            for (int ks = 0; ks < 4; ++ks)
                bfr[ct][ks] = *reinterpret_cast<const bf16x8*>(Gp + ct * 16 * 128 + ks * 32);
    }
    asm volatile("" ::: "memory");   // pin G-loads before stage issues

    const char* Abase = (const char*)(Abf + (size_t)bmg * 4 * 128 * 128);

    // stage K-half s (tile s>>1, half s&1) into buf s%3; 4 x 16B per thread.
    // LDS[row][b] = global[row][h*128 + (b ^ ((row&7)<<4))]  (16B-chunk XOR)
    auto stage = [&](int s) {
        const int it = s >> 1, h = s & 1, buf = s % 3;
        char* lbase = (char*)&sA[0] + buf * 16384;
#pragma unroll
        for (int j = 0; j < 4; ++j) {
            int f = (j * 256 + tid) * 16;
            int row = f >> 7;
            int inner = (f & 127) ^ ((row & 7) << 4);
            gll16(Abase + (size_t)it * 32768 + row * 256 + h * 128 + inner, lbase + f);
        }
    };

    f32x4 acc[4][4];
#pragma unroll
    for (int rt = 0; rt < 4; ++rt)
#pragma unroll
        for (int ct = 0; ct < 4; ++ct)
            acc[rt][ct] = (f32x4){0.f, 0.f, 0.f, 0.f};

    auto compute = [&](int s) {
        const int buf = s % 3, ksb = (s & 1) * 2;
        const char* lbase = (const char*)&sA[0] + buf * 16384;
#pragma unroll
        for (int kk = 0; kk < 2; ++kk) {
            const int kb = (kk * 64 + g * 16) ^ ((rr & 7) << 4);
            bf16x8 a[4];
#pragma unroll
            for (int rt = 0; rt < 4; ++rt)
                a[rt] = *reinterpret_cast<const bf16x8*>(lbase + (wr * 64 + rt * 16 + rr) * 128 + kb);
#pragma unroll
            for (int rt = 0; rt < 4; ++rt)
#pragma unroll
                for (int ct = 0; ct < 4; ++ct)
                    acc[rt][ct] = __builtin_amdgcn_mfma_f32_16x16x32_bf16(
                        a[rt], bfr[ct][ksb + kk], acc[rt][ct], 0, 0, 0);
        }
    };

    auto epilogue = [&](int it) {
        const int m = (bmg * 4 + it) * 2 + wr;
        const int n = bn * 2 + wc;
        float* obase = out + (size_t)m * 4096 + n * 64;
#pragma unroll
        for (int rt = 0; rt < 4; ++rt) {
            float v[4];
#pragma unroll
            for (int j = 0; j < 4; ++j)
                v[j] = fmaxf(fmaxf(acc[rt][0][j], acc[rt][1][j]),
                             fmaxf(acc[rt][2][j], acc[rt][3][j]));
#pragma unroll
            for (int off = 8; off >= 1; off >>= 1)
#pragma unroll
                for (int j = 0; j < 4; ++j)
                    v[j] = fmaxf(v[j], __shfl_xor(v[j], off));
            if (rr == 0) {
                float4 o;
                o.x = fmaxf(v[0], 0.f) + EPS_ADD;
                o.y = fmaxf(v[1], 0.f) + EPS_ADD;
                o.z = fmaxf(v[2], 0.f) + EPS_ADD;
                o.w = fmaxf(v[3], 0.f) + EPS_ADD;
                *reinterpret_cast<float4*>(obase + rt * 16 + g * 4) = o;
            }
#pragma unroll
            for (int ct = 0; ct < 4; ++ct)
                acc[rt][ct] = (f32x4){0.f, 0.f, 0.f, 0.f};
        }
    };

    // ---- prologue: stage(0), stage(1) in flight ----
    stage(0);
    stage(1);

    // ---- 8 phases: wait / barrier / compute / stage(s+2) / [epilogue] ----
    WAITV(4); __builtin_amdgcn_s_barrier(); SB0;   // drains G + stage0
    compute(0); SB0; stage(2); SB0;

    WAITV(4); __builtin_amdgcn_s_barrier(); SB0;   // drains stage1
    compute(1); SB0; stage(3); epilogue(0); SB0;

    WAITV(8); __builtin_amdgcn_s_barrier(); SB0;   // drains stage2
    compute(2); SB0; stage(4); SB0;

    WAITV(8); __builtin_amdgcn_s_barrier(); SB0;   // drains stage3
    compute(3); SB0; stage(5); epilogue(1); SB0;

    WAITV(8); __builtin_amdgcn_s_barrier(); SB0;   // drains S0 + stage4
    compute(4); SB0; stage(6); SB0;

    WAITV(8); __builtin_amdgcn_s_barrier(); SB0;   // drains stage5
    compute(5); SB0; stage(7); epilogue(2); SB0;

    WAITV(8); __builtin_amdgcn_s_barrier(); SB0;   // drains S1 + stage6
    compute(6); SB0;

    WAITV(4); __builtin_amdgcn_s_barrier(); SB0;   // drains stage7 (leaves S2)
    compute(7); SB0; epilogue(3);
}

// ---------------------------------------------------------------------------
extern "C" void kernel_launch(void* const* d_in, const int* in_sizes, int n_in,
                              void* d_out, int out_size, void* d_ws, size_t ws_size,
                              hipStream_t stream) {
    const float* A  = (const float*)d_in[0];
    const float* B  = (const float*)d_in[1];
    const float* Wg = (const float*)d_in[2];
    float* out = (float*)d_out;

    bf16* Abf = (bf16*)d_ws;                                        // 32768 x 128 bf16 = 8 MiB
    bf16* Gbf = (bf16*)((char*)d_ws + (size_t)Mdim * Pdim * Cdim * sizeof(bf16)); // 4096 x 128 bf16

    prep_A_kernel<<<Mdim, 256, 0, stream>>>(A, Abf);
    prep_G_kernel<<<256, 256, 0, stream>>>(B, Wg, Gbf);

    // rows = M*P = 32768 -> 64 groups of 512; cols = N*P = 4096 -> 32 tiles of 128
    constexpr int GEMM_GRID = (Mdim * Pdim / 512) * (Ndim * Pdim / 128);  // 2048
    gemm_max_kernel<<<GEMM_GRID, 256, 0, stream>>>(Abf, Gbf, out);
}